// Round 1
// baseline (63.921 us; speedup 1.0000x reference)
//
#include <hip/hip_runtime.h>

typedef __bf16 bf16;
typedef __bf16 bf16x4 __attribute__((ext_vector_type(4)));
typedef __bf16 bf16x8 __attribute__((ext_vector_type(8)));
typedef float f32x4 __attribute__((ext_vector_type(4)));

#define SEQ 1024
#define EMB 1024
#define NH 16
#define HD 64
#define M2 2047   // 2*MAX_POS - 1
#define MPAD 2048

// ---------------------------------------------------------------------------
// Kernel 1: P[MPAD][EMB] (bf16) = gather(posEmb) @ W
// gather row m -> clamp(m, 0, 2046)  (identity for m<2047; row 2047 = pad)
// 64x64 tile per block, 4 waves each 32x32, K-loop of 64.
// ---------------------------------------------------------------------------
__global__ __launch_bounds__(256) void gemm1_kernel(const float* __restrict__ posEmb,
                                                    const float* __restrict__ W,
                                                    bf16* __restrict__ P) {
  __shared__ bf16 As[64][72];   // emb tile  [m][k], +8 pad
  __shared__ bf16 Bs[64][72];   // W^T tile  [n][k], +8 pad
  const int tid  = threadIdx.x;
  const int lane = tid & 63;
  const int wave = tid >> 6;
  const int wr = wave >> 1, wc = wave & 1;
  const int m0 = blockIdx.y * 64;
  const int n0 = blockIdx.x * 64;

  f32x4 acc[2][2] = {};

  for (int k0 = 0; k0 < EMB; k0 += 64) {
    // ---- stage A (rows m0..m0+63, cols k0..k0+63), f32 -> bf16
    {
      const int row = tid >> 2;
      const int c0  = (tid & 3) * 16;
      int g = m0 + row;
      if (g > M2 - 1) g = M2 - 1;          // clamp (pad row duplicates 2046)
      const float4* src = reinterpret_cast<const float4*>(posEmb + (size_t)g * EMB + k0 + c0);
      #pragma unroll
      for (int i = 0; i < 4; ++i) {
        float4 v = src[i];
        bf16x4 bb = { (bf16)v.x, (bf16)v.y, (bf16)v.z, (bf16)v.w };
        *reinterpret_cast<bf16x4*>(&As[row][c0 + 4 * i]) = bb;
      }
    }
    // ---- stage W^T: Bs[n][k] = W[k0+k][n0+n]; coalesced reads along n
    {
      const int n  = tid & 63;
      const int kg = tid >> 6;   // 0..3 -> k = kg*16 .. +15
      #pragma unroll
      for (int u = 0; u < 4; ++u) {
        bf16x4 bb;
        #pragma unroll
        for (int e = 0; e < 4; ++e) {
          int k = kg * 16 + u * 4 + e;
          bb[e] = (bf16)W[(size_t)(k0 + k) * EMB + n0 + n];
        }
        *reinterpret_cast<bf16x4*>(&Bs[n][kg * 16 + u * 4]) = bb;
      }
    }
    __syncthreads();
    #pragma unroll
    for (int ks = 0; ks < 2; ++ks) {
      bf16x8 a[2], b[2];
      #pragma unroll
      for (int x = 0; x < 2; ++x) {
        a[x] = *reinterpret_cast<const bf16x8*>(&As[wr * 32 + x * 16 + (lane & 15)][ks * 32 + 8 * (lane >> 4)]);
        b[x] = *reinterpret_cast<const bf16x8*>(&Bs[wc * 32 + x * 16 + (lane & 15)][ks * 32 + 8 * (lane >> 4)]);
      }
      #pragma unroll
      for (int x = 0; x < 2; ++x)
        #pragma unroll
        for (int y = 0; y < 2; ++y)
          acc[x][y] = __builtin_amdgcn_mfma_f32_16x16x32_bf16(a[x], b[y], acc[x][y], 0, 0, 0);
    }
    __syncthreads();
  }

  #pragma unroll
  for (int x = 0; x < 2; ++x)
    #pragma unroll
    for (int y = 0; y < 2; ++y)
      #pragma unroll
      for (int r = 0; r < 4; ++r) {
        int row = m0 + wr * 32 + x * 16 + (lane >> 4) * 4 + r;
        int col = n0 + wc * 32 + y * 16 + (lane & 15);
        P[(size_t)row * EMB + col] = (bf16)acc[x][y][r];
      }
}

// ---------------------------------------------------------------------------
// Kernel 2: band GEMM + relative shift + scatter store.
// Block = (tm, it, h*2+b). Computes score tile [i0..i0+63] x [m0..m0+63],
// K=64 full. Element (i,m) -> out j = m - (SEQ-1) + i if 0<=j<SEQ.
// m0 = (SEQ-1) - (i0+63) + tm*64 ; tm in [0,17) covers the whole band.
// ---------------------------------------------------------------------------
__global__ __launch_bounds__(256) void band_kernel(const float* __restrict__ q,
                                                   const bf16* __restrict__ P,
                                                   float* __restrict__ out) {
  __shared__ bf16 Qs[64][72];
  __shared__ bf16 Ps[64][72];
  const int tid  = threadIdx.x;
  const int lane = tid & 63;
  const int wave = tid >> 6;
  const int wr = wave >> 1, wc = wave & 1;

  const int tm = blockIdx.x;        // 0..16
  const int i0 = blockIdx.y * 64;   // i-tile origin
  const int hb = blockIdx.z;        // h*2 + b
  const int h  = hb >> 1;
  const int b  = hb & 1;
  const int m0 = (SEQ - 1) - (i0 + 63) + tm * 64;   // >= 0, <= 1984

  // ---- stage Q rows (f32 -> bf16): q viewed as [NH][2*SEQ][HD] raw
  {
    const int row = tid >> 2;
    const int c0  = (tid & 3) * 16;
    const float4* src = reinterpret_cast<const float4*>(
        q + ((size_t)(h * (2 * SEQ) + b * SEQ + i0 + row)) * HD + c0);
    #pragma unroll
    for (int i = 0; i < 4; ++i) {
      float4 v = src[i];
      bf16x4 bb = { (bf16)v.x, (bf16)v.y, (bf16)v.z, (bf16)v.w };
      *reinterpret_cast<bf16x4*>(&Qs[row][c0 + 4 * i]) = bb;
    }
  }
  // ---- stage P tile (bf16 direct): rows m0..m0+63, cols h*64..h*64+63
  {
    const int row = tid >> 2;
    const int c0  = (tid & 3) * 16;   // 16 bf16 = 32 B per thread
    const int4* src = reinterpret_cast<const int4*>(P + (size_t)(m0 + row) * EMB + h * HD + c0);
    *reinterpret_cast<int4*>(&Ps[row][c0])     = src[0];
    *reinterpret_cast<int4*>(&Ps[row][c0 + 8]) = src[1];
  }
  __syncthreads();

  f32x4 acc[2][2] = {};
  #pragma unroll
  for (int ks = 0; ks < 2; ++ks) {
    bf16x8 a[2], bb[2];
    #pragma unroll
    for (int x = 0; x < 2; ++x) {
      a[x]  = *reinterpret_cast<const bf16x8*>(&Qs[wr * 32 + x * 16 + (lane & 15)][ks * 32 + 8 * (lane >> 4)]);
      bb[x] = *reinterpret_cast<const bf16x8*>(&Ps[wc * 32 + x * 16 + (lane & 15)][ks * 32 + 8 * (lane >> 4)]);
    }
    #pragma unroll
    for (int x = 0; x < 2; ++x)
      #pragma unroll
      for (int y = 0; y < 2; ++y)
        acc[x][y] = __builtin_amdgcn_mfma_f32_16x16x32_bf16(a[x], bb[y], acc[x][y], 0, 0, 0);
  }

  // ---- epilogue: shift + masked scatter
  const size_t outbase = (size_t)hb << 20;   // hb * SEQ * SEQ
  #pragma unroll
  for (int x = 0; x < 2; ++x)
    #pragma unroll
    for (int y = 0; y < 2; ++y)
      #pragma unroll
      for (int r = 0; r < 4; ++r) {
        int il = wr * 32 + x * 16 + (lane >> 4) * 4 + r;
        int ml = wc * 32 + y * 16 + (lane & 15);
        int i = i0 + il;
        int m = m0 + ml;
        int j = m - (SEQ - 1) + i;
        if (j >= 0 && j < SEQ)
          out[outbase + (size_t)i * SEQ + j] = acc[x][y][r];
      }
}

extern "C" void kernel_launch(void* const* d_in, const int* in_sizes, int n_in,
                              void* d_out, int out_size, void* d_ws, size_t ws_size,
                              hipStream_t stream) {
  const float* query  = (const float*)d_in[0];   // [2,16,1024,64]
  const float* posEmb = (const float*)d_in[1];   // [2047,1024]
  const float* W      = (const float*)d_in[2];   // [1024,1024]
  float* out = (float*)d_out;                    // [2,16,1024,1024] (raw-reshape layout)
  bf16* P = (bf16*)d_ws;                         // [2048][1024] bf16 = 4 MB

  gemm1_kernel<<<dim3(16, 32), 256, 0, stream>>>(posEmb, W, P);
  band_kernel<<<dim3(17, 16, 32), 256, 0, stream>>>(query, P, out);
}

// Round 2
// 61.259 us; speedup vs baseline: 1.0435x; 1.0435x over previous
//
#include <hip/hip_runtime.h>

typedef __bf16 bf16;
typedef __bf16 bf16x4 __attribute__((ext_vector_type(4)));
typedef __bf16 bf16x8 __attribute__((ext_vector_type(8)));
typedef float f32x4 __attribute__((ext_vector_type(4)));

#define SEQ 1024
#define EMB 1024
#define NH 16
#define HD 64
#define M2 2047   // 2*MAX_POS - 1

// ---------------------------------------------------------------------------
// Kernel 1 (UNCHANGED from round 1): P[2048][1024] (bf16) = gather(posEmb) @ W
// ---------------------------------------------------------------------------
__global__ __launch_bounds__(256) void gemm1_kernel(const float* __restrict__ posEmb,
                                                    const float* __restrict__ W,
                                                    bf16* __restrict__ P) {
  __shared__ bf16 As[64][72];
  __shared__ bf16 Bs[64][72];
  const int tid  = threadIdx.x;
  const int lane = tid & 63;
  const int wave = tid >> 6;
  const int wr = wave >> 1, wc = wave & 1;
  const int m0 = blockIdx.y * 64;
  const int n0 = blockIdx.x * 64;

  f32x4 acc[2][2] = {};

  for (int k0 = 0; k0 < EMB; k0 += 64) {
    {
      const int row = tid >> 2;
      const int c0  = (tid & 3) * 16;
      int g = m0 + row;
      if (g > M2 - 1) g = M2 - 1;
      const float4* src = reinterpret_cast<const float4*>(posEmb + (size_t)g * EMB + k0 + c0);
      #pragma unroll
      for (int i = 0; i < 4; ++i) {
        float4 v = src[i];
        bf16x4 bb = { (bf16)v.x, (bf16)v.y, (bf16)v.z, (bf16)v.w };
        *reinterpret_cast<bf16x4*>(&As[row][c0 + 4 * i]) = bb;
      }
    }
    {
      const int n  = tid & 63;
      const int kg = tid >> 6;
      #pragma unroll
      for (int u = 0; u < 4; ++u) {
        bf16x4 bb;
        #pragma unroll
        for (int e = 0; e < 4; ++e) {
          int k = kg * 16 + u * 4 + e;
          bb[e] = (bf16)W[(size_t)(k0 + k) * EMB + n0 + n];
        }
        *reinterpret_cast<bf16x4*>(&Bs[n][kg * 16 + u * 4]) = bb;
      }
    }
    __syncthreads();
    #pragma unroll
    for (int ks = 0; ks < 2; ++ks) {
      bf16x8 a[2], b[2];
      #pragma unroll
      for (int x = 0; x < 2; ++x) {
        a[x] = *reinterpret_cast<const bf16x8*>(&As[wr * 32 + x * 16 + (lane & 15)][ks * 32 + 8 * (lane >> 4)]);
        b[x] = *reinterpret_cast<const bf16x8*>(&Bs[wc * 32 + x * 16 + (lane & 15)][ks * 32 + 8 * (lane >> 4)]);
      }
      #pragma unroll
      for (int x = 0; x < 2; ++x)
        #pragma unroll
        for (int y = 0; y < 2; ++y)
          acc[x][y] = __builtin_amdgcn_mfma_f32_16x16x32_bf16(a[x], b[y], acc[x][y], 0, 0, 0);
    }
    __syncthreads();
  }

  #pragma unroll
  for (int x = 0; x < 2; ++x)
    #pragma unroll
    for (int y = 0; y < 2; ++y)
      #pragma unroll
      for (int r = 0; r < 4; ++r) {
        int row = m0 + wr * 32 + x * 16 + (lane >> 4) * 4 + r;
        int col = n0 + wc * 32 + y * 16 + (lane & 15);
        P[(size_t)row * EMB + col] = (bf16)acc[x][y][r];
      }
}

// ---------------------------------------------------------------------------
// Kernel 2 (REWRITTEN): band GEMM with m-loop inside the block.
//   grid = (16 i-tiles, 32 hb, 2 m-halves), block = 256 (4 waves, 32x32 each).
//   Q fragments loaded once to registers (no LDS staging, no barrier).
//   P tile double-buffered via global_load_lds (16B) with pre-swizzled source
//   (byte ^= ((row&7)<<4)) so ds_read_b128 B-frag reads are conflict-free.
// ---------------------------------------------------------------------------
__global__ __launch_bounds__(256) void band2_kernel(const float* __restrict__ q,
                                                    const bf16* __restrict__ P,
                                                    float* __restrict__ out) {
  __shared__ bf16 Pbuf[2][64 * 64];   // linear, swizzled content; 16 KB
  const int tid  = threadIdx.x;
  const int lane = tid & 63;
  const int wave = tid >> 6;
  const int wr = wave >> 1, wc = wave & 1;

  const int i0 = blockIdx.x * 64;
  const int hb = blockIdx.y;          // h*2 + b
  const int h  = hb >> 1;
  const int b  = hb & 1;

  // ---- Q fragments: direct global f32 -> bf16x8 registers.
  // a[x][ks]: row = i0 + wr*32 + x*16 + (lane&15), k = ks*32 + 8*(lane>>4)
  bf16x8 a[2][2];
  {
    const float* qbase = q + ((size_t)(h * (2 * SEQ) + b * SEQ)) * HD;
    const int row = i0 + wr * 32 + (lane & 15);
    const int kof = 8 * (lane >> 4);
    #pragma unroll
    for (int x = 0; x < 2; ++x)
      #pragma unroll
      for (int ks = 0; ks < 2; ++ks) {
        const float* src = qbase + (size_t)(row + x * 16) * HD + ks * 32 + kof;
        float4 v0 = *reinterpret_cast<const float4*>(src);
        float4 v1 = *reinterpret_cast<const float4*>(src + 4);
        bf16x8 f = { (bf16)v0.x, (bf16)v0.y, (bf16)v0.z, (bf16)v0.w,
                     (bf16)v1.x, (bf16)v1.y, (bf16)v1.z, (bf16)v1.w };
        a[x][ks] = f;
      }
  }

  const int m_base = (SEQ - 1) - (i0 + 63);     // m for t=0 (>= 0)
  const int tb = blockIdx.z * 9;                // 0 or 9
  const int te = (blockIdx.z == 0) ? 9 : 17;    // 9 or 8 tiles

  // stage tile t into Pbuf[bi]: 8 KB, 2 x global_load_lds(16B) per thread.
  auto STAGE = [&](int bi, int t) {
    const int m0 = m_base + t * 64;
    const char* Pb = reinterpret_cast<const char*>(P);
    #pragma unroll
    for (int i = 0; i < 2; ++i) {
      int s   = wave * 128 + i * 64 + lane;     // 16B-granule slot (linear dest)
      int row = s >> 3;
      int cs  = s & 7;
      int cd  = cs ^ (row & 7);                 // pre-swizzled source chunk
      const void* g = Pb + ((size_t)(m0 + row) * EMB + h * HD) * 2 + cd * 16;
      char* l = reinterpret_cast<char*>(&Pbuf[bi][0]) + (wave * 128 + i * 64) * 16;
      __builtin_amdgcn_global_load_lds(
          (const __attribute__((address_space(1))) void*)g,
          (__attribute__((address_space(3))) void*)l, 16, 0, 0);
    }
  };

  const size_t outbase = (size_t)hb << 20;      // hb * SEQ * SEQ

  STAGE(0, tb);
  __syncthreads();

  int cur = 0;
  for (int t = tb; t < te; ++t) {
    if (t + 1 < te) STAGE(cur ^ 1, t + 1);

    // ---- compute tile t from Pbuf[cur] (swizzled reads)
    const char* buf = reinterpret_cast<const char*>(&Pbuf[cur][0]);
    f32x4 acc[2][2] = {};
    #pragma unroll
    for (int ks = 0; ks < 2; ++ks) {
      bf16x8 bb[2];
      #pragma unroll
      for (int y = 0; y < 2; ++y) {
        int mrow  = wc * 32 + y * 16 + (lane & 15);
        int chunk = ks * 4 + (lane >> 4);
        int sw    = chunk ^ (mrow & 7);
        bb[y] = *reinterpret_cast<const bf16x8*>(buf + mrow * 128 + sw * 16);
      }
      #pragma unroll
      for (int x = 0; x < 2; ++x)
        #pragma unroll
        for (int y = 0; y < 2; ++y)
          acc[x][y] = __builtin_amdgcn_mfma_f32_16x16x32_bf16(a[x][ks], bb[y], acc[x][y], 0, 0, 0);
    }

    // ---- epilogue: shift + masked scatter for tile t
    const int m0 = m_base + t * 64;
    #pragma unroll
    for (int x = 0; x < 2; ++x)
      #pragma unroll
      for (int y = 0; y < 2; ++y)
        #pragma unroll
        for (int r = 0; r < 4; ++r) {
          int i = i0 + wr * 32 + x * 16 + (lane >> 4) * 4 + r;
          int m = m0 + wc * 32 + y * 16 + (lane & 15);
          int j = m - (SEQ - 1) + i;
          if ((unsigned)j < SEQ)
            out[outbase + (size_t)i * SEQ + j] = acc[x][y][r];
        }

    __syncthreads();
    cur ^= 1;
  }
}

extern "C" void kernel_launch(void* const* d_in, const int* in_sizes, int n_in,
                              void* d_out, int out_size, void* d_ws, size_t ws_size,
                              hipStream_t stream) {
  const float* query  = (const float*)d_in[0];   // [2,16,1024,64]
  const float* posEmb = (const float*)d_in[1];   // [2047,1024]
  const float* W      = (const float*)d_in[2];   // [1024,1024]
  float* out = (float*)d_out;                    // [2,16,1024,1024]
  bf16* P = (bf16*)d_ws;                         // [2048][1024] bf16 = 4 MB

  gemm1_kernel<<<dim3(16, 32), 256, 0, stream>>>(posEmb, W, P);
  band2_kernel<<<dim3(16, 32, 2), 256, 0, stream>>>(query, P, out);
}